// Round 1
// baseline (1226.811 us; speedup 1.0000x reference)
//
#include <hip/hip_runtime.h>
#include <math.h>

#define NN 100000
#define EE 1600000
#define DD 64
#define EPS 1e-5f
#define SCALEF 0.125f   // 1/sqrt(64)

// ---------------- CSR build ----------------

__global__ void hist_kernel(const int* __restrict__ ei, int* __restrict__ cnt, int E) {
    for (int e = blockIdx.x * blockDim.x + threadIdx.x; e < E; e += gridDim.x * blockDim.x)
        atomicAdd(&cnt[ei[E + e]], 1);   // dst = ei[E+e]
}

__global__ __launch_bounds__(1024) void scan_block(const int* __restrict__ deg,
                                                   int* __restrict__ out,
                                                   int* __restrict__ part, int n) {
    __shared__ int sh[1024];
    int tid = threadIdx.x;
    int gi = blockIdx.x * 1024 + tid;
    int v = (gi < n - 1) ? deg[gi] : 0;   // scan n=N+1 values, value[N]=0
    sh[tid] = v;
    __syncthreads();
    for (int off = 1; off < 1024; off <<= 1) {
        int t = (tid >= off) ? sh[tid - off] : 0;
        __syncthreads();
        sh[tid] += t;
        __syncthreads();
    }
    if (gi < n) out[gi] = sh[tid] - v;    // exclusive
    if (tid == 1023) part[blockIdx.x] = sh[1023];
}

__global__ void scan_part(int* part, int nb) {
    if (threadIdx.x == 0 && blockIdx.x == 0) {
        int run = 0;
        for (int b = 0; b < nb; b++) { int t = part[b]; part[b] = run; run += t; }
    }
}

__global__ void scan_add(int* __restrict__ out, const int* __restrict__ part, int n) {
    int i = blockIdx.x * blockDim.x + threadIdx.x;
    if (i < n) out[i] += part[i >> 10];
}

__global__ void scatter_kernel(const int* __restrict__ ei, int* __restrict__ cnt,
                               const int* __restrict__ off, int* __restrict__ csr, int E) {
    for (int e = blockIdx.x * blockDim.x + threadIdx.x; e < E; e += gridDim.x * blockDim.x) {
        int s = ei[e];
        int d = ei[E + e];
        int pos = off[d] + atomicAdd(&cnt[d], 1);
        csr[pos] = s;
    }
}

// ---------------- fused 4-matrix GEMM: q,k,v,skip = x@W + b ----------------
// 64-row tile, 256 threads, 4x4 register blocking per thread.

__global__ __launch_bounds__(256) void gemm4(const float* __restrict__ x, int N,
    const float* __restrict__ W0, const float* __restrict__ W1,
    const float* __restrict__ W2, const float* __restrict__ W3,
    const float* __restrict__ b0, const float* __restrict__ b1,
    const float* __restrict__ b2, const float* __restrict__ b3,
    float* __restrict__ o0, float* __restrict__ o1,
    float* __restrict__ o2, float* __restrict__ o3)
{
    __shared__ __align__(16) float xt[64][66];   // padded: rows hit distinct banks
    __shared__ __align__(16) float wt[64][64];   // row-major, float4 col reads

    int tid = threadIdx.x;
    int row0 = blockIdx.x * 64;

    // stage x tile (read BEFORE any output write: o0 may alias x)
    for (int idx = tid; idx < 64 * 64; idx += 256) {
        int r = idx >> 6, c = idx & 63;
        int gr = row0 + r;
        xt[r][c] = (gr < N) ? x[gr * 64 + c] : 0.f;
    }

    const float* Wm[4] = {W0, W1, W2, W3};
    const float* bm[4] = {b0, b1, b2, b3};
    float* om[4] = {o0, o1, o2, o3};

    int tr = tid >> 4, tc = tid & 15;
    int r0 = tr * 4, c0 = tc * 4;

#pragma unroll
    for (int m = 0; m < 4; m++) {
        __syncthreads();
        for (int idx = tid; idx < 4096; idx += 256)
            wt[idx >> 6][idx & 63] = Wm[m][idx];
        __syncthreads();

        float acc[4][4] = {};
#pragma unroll
        for (int kk = 0; kk < 64; kk++) {
            float4 wv = *reinterpret_cast<const float4*>(&wt[kk][c0]);
            float xv0 = xt[r0 + 0][kk];
            float xv1 = xt[r0 + 1][kk];
            float xv2 = xt[r0 + 2][kk];
            float xv3 = xt[r0 + 3][kk];
            acc[0][0] += xv0 * wv.x; acc[0][1] += xv0 * wv.y; acc[0][2] += xv0 * wv.z; acc[0][3] += xv0 * wv.w;
            acc[1][0] += xv1 * wv.x; acc[1][1] += xv1 * wv.y; acc[1][2] += xv1 * wv.z; acc[1][3] += xv1 * wv.w;
            acc[2][0] += xv2 * wv.x; acc[2][1] += xv2 * wv.y; acc[2][2] += xv2 * wv.z; acc[2][3] += xv2 * wv.w;
            acc[3][0] += xv3 * wv.x; acc[3][1] += xv3 * wv.y; acc[3][2] += xv3 * wv.z; acc[3][3] += xv3 * wv.w;
        }
        float4 bb = *reinterpret_cast<const float4*>(&bm[m][c0]);
#pragma unroll
        for (int i = 0; i < 4; i++) {
            int gr = row0 + r0 + i;
            if (gr < N) {
                float4 o;
                o.x = acc[i][0] + bb.x;
                o.y = acc[i][1] + bb.y;
                o.z = acc[i][2] + bb.z;
                o.w = acc[i][3] + bb.w;
                *reinterpret_cast<float4*>(&om[m][gr * 64 + c0]) = o;
            }
        }
    }
}

// ---------------- fused node kernel: attention + skip + relu + residual + LN ----------------
// one wave per dst node; lane = feature dim.

__device__ __forceinline__ float wsum(float v) {
#pragma unroll
    for (int o = 32; o > 0; o >>= 1) v += __shfl_xor(v, o);
    return v;
}

__global__ __launch_bounds__(256) void node_attn(
    const int* __restrict__ off, const int* __restrict__ csr_src,
    const float* __restrict__ q, const float* __restrict__ k, const float* __restrict__ v,
    const float* __restrict__ xs, const float* __restrict__ gamma, const float* __restrict__ beta,
    float* __restrict__ xinit, float* __restrict__ xout, int layer, int N)
{
    int wid = (blockIdx.x * blockDim.x + threadIdx.x) >> 6;
    int lane = threadIdx.x & 63;
    if (wid >= N) return;
    int n = wid;
    int e0 = off[n], e1 = off[n + 1];

    float qd = q[n * 64 + lane];

    float m = -INFINITY, ssum = 0.f, acc = 0.f;
    for (int base = e0; base < e1; base += 64) {
        int cnt = min(64, e1 - base);
        int mysrc = (lane < cnt) ? csr_src[base + lane] : 0;
        for (int j = 0; j < cnt; j++) {
            int src = __shfl(mysrc, j);
            float kk = k[src * 64 + lane];
            float dot = qd * kk;
#pragma unroll
            for (int o = 32; o > 0; o >>= 1) dot += __shfl_xor(dot, o);
            dot *= SCALEF;
            float vv = v[src * 64 + lane];
            float mnew = fmaxf(m, dot);
            float c = __expf(m - mnew);     // exp(-inf)=0 on first edge
            float p = __expf(dot - mnew);
            ssum = ssum * c + p;
            acc  = acc * c + p * vv;
            m = mnew;
        }
    }
    float agg = (e1 > e0) ? acc / ssum : 0.f;

    float h = agg + xs[n * 64 + lane];
    h = fmaxf(h, 0.f);                       // relu
    if (layer == 0) xinit[n * 64 + lane] = h;
    else            h += xinit[n * 64 + lane];

    // LayerNorm across 64 lanes
    float mu  = wsum(h) * (1.f / 64.f);
    float d   = h - mu;
    float var = wsum(d * d) * (1.f / 64.f);
    float o   = d * rsqrtf(var + EPS) * gamma[lane] + beta[lane];
    xout[n * 64 + lane] = o;
}

// ---------------- launch ----------------

extern "C" void kernel_launch(void* const* d_in, const int* in_sizes, int n_in,
                              void* d_out, int out_size, void* d_ws, size_t ws_size,
                              hipStream_t stream) {
    const float* x     = (const float*)d_in[0];
    const int*   ei    = (const int*)d_in[1];
    const float* Wq    = (const float*)d_in[2];
    const float* bq    = (const float*)d_in[3];
    const float* Wk    = (const float*)d_in[4];
    const float* bk    = (const float*)d_in[5];
    const float* Wv    = (const float*)d_in[6];
    const float* bv    = (const float*)d_in[7];
    const float* Wsk   = (const float*)d_in[8];
    const float* bsk   = (const float*)d_in[9];
    const float* gamma = (const float*)d_in[10];
    const float* beta  = (const float*)d_in[11];
    float* out = (float*)d_out;

    const int N = NN, E = EE;
    const size_t ND = (size_t)N * DD;

    char* p = (char*)d_ws;
    float* fQ = (float*)p; p += ND * 4;   // q, aliased as layer x-output
    float* fK = (float*)p; p += ND * 4;
    float* fV = (float*)p; p += ND * 4;
    float* fS = (float*)p; p += ND * 4;   // skip = x@Ws + bs
    float* fI = (float*)p; p += ND * 4;   // x_init
    int* iOff = (int*)p;   p += (size_t)(N + 1) * 4;
    int* iCnt = (int*)p;   p += (size_t)N * 4;
    int* iPar = (int*)p;   p += 1024 * 4;
    int* iSrc = (int*)p;   p += (size_t)E * 4;

    // ---- CSR build (dst is layer-invariant) ----
    hipMemsetAsync(iCnt, 0, (size_t)N * 4, stream);
    hist_kernel<<<2048, 256, 0, stream>>>(ei, iCnt, E);
    int scan_n = N + 1;
    int nb = (scan_n + 1023) / 1024;                 // 98
    scan_block<<<nb, 1024, 0, stream>>>(iCnt, iOff, iPar, scan_n);
    scan_part<<<1, 64, 0, stream>>>(iPar, nb);
    scan_add<<<(scan_n + 255) / 256, 256, 0, stream>>>(iOff, iPar, scan_n);
    hipMemsetAsync(iCnt, 0, (size_t)N * 4, stream);
    scatter_kernel<<<2048, 256, 0, stream>>>(ei, iCnt, iOff, iSrc, E);

    // ---- 3 layers ----
    const float* xin = x;
    for (int l = 0; l < 3; l++) {
        gemm4<<<(N + 63) / 64, 256, 0, stream>>>(xin, N,
            Wq + l * 4096, Wk + l * 4096, Wv + l * 4096, Wsk + l * 4096,
            bq + l * 64,   bk + l * 64,   bv + l * 64,   bsk + l * 64,
            fQ, fK, fV, fS);
        float* xout = (l == 2) ? out : fQ;           // fQ doubles as next x
        node_attn<<<(N + 3) / 4, 256, 0, stream>>>(iOff, iSrc, fQ, fK, fV, fS,
            gamma + l * 64, beta + l * 64, fI, xout, l, N);
        xin = fQ;
    }
}

// Round 2
// 675.018 us; speedup vs baseline: 1.8174x; 1.8174x over previous
//
#include <hip/hip_runtime.h>
#include <math.h>

#define NN 100000
#define EE 1600000
#define EPS 1e-5f
#define SCALEF 0.125f   // 1/sqrt(64)

typedef __attribute__((ext_vector_type(4))) float f32x4;
typedef __attribute__((ext_vector_type(8))) short bf16x8;

__device__ __forceinline__ unsigned short f2bf_rne(float f) {
    unsigned u = __builtin_bit_cast(unsigned, f);
    u += 0x7FFFu + ((u >> 16) & 1u);
    return (unsigned short)(u >> 16);
}
__device__ __forceinline__ float bf2f(unsigned short h) {
    return __builtin_bit_cast(float, ((unsigned)h) << 16);
}

// ---------------- CSR build ----------------

__global__ void hist_kernel(const int* __restrict__ ei, int* __restrict__ cnt, int E) {
    for (int e = blockIdx.x * blockDim.x + threadIdx.x; e < E; e += gridDim.x * blockDim.x)
        atomicAdd(&cnt[ei[E + e]], 1);
}

__global__ __launch_bounds__(1024) void scan_block(const int* __restrict__ deg,
                                                   int* __restrict__ out,
                                                   int* __restrict__ part, int n) {
    __shared__ int sh[1024];
    int tid = threadIdx.x;
    int gi = blockIdx.x * 1024 + tid;
    int v = (gi < n - 1) ? deg[gi] : 0;
    sh[tid] = v;
    __syncthreads();
    for (int off = 1; off < 1024; off <<= 1) {
        int t = (tid >= off) ? sh[tid - off] : 0;
        __syncthreads();
        sh[tid] += t;
        __syncthreads();
    }
    if (gi < n) out[gi] = sh[tid] - v;
    if (tid == 1023) part[blockIdx.x] = sh[1023];
}

__global__ void scan_part(int* part, int nb) {
    if (threadIdx.x == 0 && blockIdx.x == 0) {
        int run = 0;
        for (int b = 0; b < nb; b++) { int t = part[b]; part[b] = run; run += t; }
    }
}

__global__ void scan_add(int* __restrict__ out, const int* __restrict__ part, int n) {
    int i = blockIdx.x * blockDim.x + threadIdx.x;
    if (i < n) out[i] += part[i >> 10];
}

__global__ void scatter_kernel(const int* __restrict__ ei, int* __restrict__ cnt,
                               const int* __restrict__ off, int* __restrict__ csr, int E) {
    for (int e = blockIdx.x * blockDim.x + threadIdx.x; e < E; e += gridDim.x * blockDim.x) {
        int s = ei[e];
        int d = ei[E + e];
        int pos = off[d] + atomicAdd(&cnt[d], 1);
        csr[pos] = s;
    }
}

// ---------------- fused 4-matrix GEMM via split-bf16 MFMA ----------------
// 64-row tile, 4 waves; wave w computes its matrix's full 64x64 output.
// x = x_hi + x_lo (bf16 pair) => x@W via 3 MFMAs per tile: ~fp32 precision.

__global__ __launch_bounds__(256) void gemm4_mfma(const float* __restrict__ x, int N,
    const float* __restrict__ Wq, const float* __restrict__ Wk,
    const float* __restrict__ Wv, const float* __restrict__ Ws,
    const float* __restrict__ bq, const float* __restrict__ bk,
    const float* __restrict__ bv, const float* __restrict__ bs,
    float* __restrict__ oq, unsigned short* __restrict__ ok,
    unsigned short* __restrict__ ov, float* __restrict__ os)
{
    __shared__ unsigned short xhi[64][80];   // row stride 160B: 16B-aligned, conflict-light
    __shared__ unsigned short xlo[64][80];

    int tid = threadIdx.x;
    int row0 = blockIdx.x * 64;

    // stage x tile as bf16 hi/lo (read before any aliased write; per-block rows only)
#pragma unroll
    for (int i = 0; i < 16; i++) {
        int idx = tid + i * 256;
        int r = idx >> 6, c = idx & 63;
        float f = (row0 + r < N) ? x[(size_t)(row0 + r) * 64 + c] : 0.f;
        unsigned short h = f2bf_rne(f);
        xhi[r][c] = h;
        xlo[r][c] = f2bf_rne(f - bf2f(h));
    }
    __syncthreads();

    int w = tid >> 6, l = tid & 63;
    int colb = l & 15, kg = l >> 4;
    const float* W    = (w == 0) ? Wq : (w == 1) ? Wk : (w == 2) ? Wv : Ws;
    const float* bias = (w == 0) ? bq : (w == 1) ? bk : (w == 2) ? bv : bs;

    // B fragments from global W (L2-hot, 16KB): col = ct*16+(l&15), k = ks*32+(l>>4)*8+e
    bf16x8 bh[4][2], bl[4][2];
#pragma unroll
    for (int ct = 0; ct < 4; ct++)
#pragma unroll
        for (int ks = 0; ks < 2; ks++) {
            int col = ct * 16 + colb;
            bf16x8 hh, ll;
#pragma unroll
            for (int e = 0; e < 8; e++) {
                int kk = ks * 32 + kg * 8 + e;
                float f = W[kk * 64 + col];
                unsigned short h = f2bf_rne(f);
                hh[e] = (short)h;
                ll[e] = (short)f2bf_rne(f - bf2f(h));
            }
            bh[ct][ks] = hh;
            bl[ct][ks] = ll;
        }

    f32x4 acc[4][4] = {};
#pragma unroll
    for (int rt = 0; rt < 4; rt++) {
        int r = rt * 16 + colb;
#pragma unroll
        for (int ks = 0; ks < 2; ks++) {
            bf16x8 ah = *(const bf16x8*)&xhi[r][ks * 32 + kg * 8];
            bf16x8 al = *(const bf16x8*)&xlo[r][ks * 32 + kg * 8];
#pragma unroll
            for (int ct = 0; ct < 4; ct++) {
                acc[rt][ct] = __builtin_amdgcn_mfma_f32_16x16x32_bf16(ah, bh[ct][ks], acc[rt][ct], 0, 0, 0);
                acc[rt][ct] = __builtin_amdgcn_mfma_f32_16x16x32_bf16(ah, bl[ct][ks], acc[rt][ct], 0, 0, 0);
                acc[rt][ct] = __builtin_amdgcn_mfma_f32_16x16x32_bf16(al, bh[ct][ks], acc[rt][ct], 0, 0, 0);
            }
        }
    }

    // C/D layout (verified m89/m91): col = lane&15, row = (lane>>4)*4 + j
#pragma unroll
    for (int rt = 0; rt < 4; rt++)
#pragma unroll
        for (int ct = 0; ct < 4; ct++) {
            int col = ct * 16 + colb;
            float bb = bias[col];
#pragma unroll
            for (int j = 0; j < 4; j++) {
                int gr = row0 + rt * 16 + kg * 4 + j;
                if (gr < N) {
                    float val = acc[rt][ct][j] + bb;
                    size_t o = (size_t)gr * 64 + col;
                    if (w == 0)      oq[o] = val;
                    else if (w == 1) ok[o] = f2bf_rne(val);
                    else if (w == 2) ov[o] = f2bf_rne(val);
                    else             os[o] = val;
                }
            }
        }
}

// ---------------- fused node kernel: 16-lane group per node, float4 per lane ----------------

__global__ __launch_bounds__(256) void node_attn(
    const int* __restrict__ off, const int* __restrict__ csr,
    const float* __restrict__ q, const unsigned short* __restrict__ k,
    const unsigned short* __restrict__ v, const float* __restrict__ xs,
    const float* __restrict__ gamma, const float* __restrict__ beta,
    float* __restrict__ xinit, float* __restrict__ xout, int layer, int N)
{
    int node = (blockIdx.x * blockDim.x + threadIdx.x) >> 4;
    int sl = threadIdx.x & 15;
    if (node >= N) return;
    int e0 = off[node], e1 = off[node + 1];
    size_t nb = (size_t)node * 64 + sl * 4;

    f32x4 qv = *(const f32x4*)&q[nb];
    float m = -INFINITY, ssum = 0.f;
    f32x4 acc = {0.f, 0.f, 0.f, 0.f};

#define DOT16(d, kv)                                                        \
    {                                                                       \
        d = qv.x * bf2f(kv.x) + qv.y * bf2f(kv.y) +                         \
            qv.z * bf2f(kv.z) + qv.w * bf2f(kv.w);                          \
        d += __shfl_xor(d, 1); d += __shfl_xor(d, 2);                       \
        d += __shfl_xor(d, 4); d += __shfl_xor(d, 8);                       \
        d *= SCALEF;                                                        \
    }
#define UPDATE(d, vv)                                                       \
    {                                                                       \
        float mn = fmaxf(m, d);                                             \
        float c = __expf(m - mn), p = __expf(d - mn);                       \
        ssum = ssum * c + p;                                                \
        acc.x = acc.x * c + p * bf2f(vv.x);                                 \
        acc.y = acc.y * c + p * bf2f(vv.y);                                 \
        acc.z = acc.z * c + p * bf2f(vv.z);                                 \
        acc.w = acc.w * c + p * bf2f(vv.w);                                 \
        m = mn;                                                             \
    }

    int e = e0;
    for (; e + 1 < e1; e += 2) {
        int s0 = csr[e], s1 = csr[e + 1];
        ushort4 k0 = *(const ushort4*)&k[(size_t)s0 * 64 + sl * 4];
        ushort4 v0 = *(const ushort4*)&v[(size_t)s0 * 64 + sl * 4];
        ushort4 k1 = *(const ushort4*)&k[(size_t)s1 * 64 + sl * 4];
        ushort4 v1 = *(const ushort4*)&v[(size_t)s1 * 64 + sl * 4];
        float d0, d1;
        DOT16(d0, k0);
        DOT16(d1, k1);
        UPDATE(d0, v0);
        UPDATE(d1, v1);
    }
    if (e < e1) {
        int s0 = csr[e];
        ushort4 k0 = *(const ushort4*)&k[(size_t)s0 * 64 + sl * 4];
        ushort4 v0 = *(const ushort4*)&v[(size_t)s0 * 64 + sl * 4];
        float d0;
        DOT16(d0, k0);
        UPDATE(d0, v0);
    }

    float inv = (e1 > e0) ? 1.f / ssum : 0.f;
    f32x4 sk = *(const f32x4*)&xs[nb];
    f32x4 h;
    h.x = fmaxf(acc.x * inv + sk.x, 0.f);
    h.y = fmaxf(acc.y * inv + sk.y, 0.f);
    h.z = fmaxf(acc.z * inv + sk.z, 0.f);
    h.w = fmaxf(acc.w * inv + sk.w, 0.f);
    if (layer == 0) {
        *(f32x4*)&xinit[nb] = h;
    } else {
        f32x4 xi = *(const f32x4*)&xinit[nb];
        h.x += xi.x; h.y += xi.y; h.z += xi.z; h.w += xi.w;
    }

    // LayerNorm over 64 features (4 per lane x 16 lanes)
    float s1 = h.x + h.y + h.z + h.w;
    s1 += __shfl_xor(s1, 1); s1 += __shfl_xor(s1, 2);
    s1 += __shfl_xor(s1, 4); s1 += __shfl_xor(s1, 8);
    float mu = s1 * (1.f / 64.f);
    f32x4 d;
    d.x = h.x - mu; d.y = h.y - mu; d.z = h.z - mu; d.w = h.w - mu;
    float s2 = d.x * d.x + d.y * d.y + d.z * d.z + d.w * d.w;
    s2 += __shfl_xor(s2, 1); s2 += __shfl_xor(s2, 2);
    s2 += __shfl_xor(s2, 4); s2 += __shfl_xor(s2, 8);
    float rs = rsqrtf(s2 * (1.f / 64.f) + EPS);
    f32x4 g = *(const f32x4*)&gamma[sl * 4];
    f32x4 bb = *(const f32x4*)&beta[sl * 4];
    f32x4 o;
    o.x = d.x * rs * g.x + bb.x;
    o.y = d.y * rs * g.y + bb.y;
    o.z = d.z * rs * g.z + bb.z;
    o.w = d.w * rs * g.w + bb.w;
    *(f32x4*)&xout[nb] = o;
}

// ---------------- launch ----------------

extern "C" void kernel_launch(void* const* d_in, const int* in_sizes, int n_in,
                              void* d_out, int out_size, void* d_ws, size_t ws_size,
                              hipStream_t stream) {
    const float* x     = (const float*)d_in[0];
    const int*   ei    = (const int*)d_in[1];
    const float* Wq    = (const float*)d_in[2];
    const float* bq    = (const float*)d_in[3];
    const float* Wk    = (const float*)d_in[4];
    const float* bk    = (const float*)d_in[5];
    const float* Wv    = (const float*)d_in[6];
    const float* bv    = (const float*)d_in[7];
    const float* Wsk   = (const float*)d_in[8];
    const float* bsk   = (const float*)d_in[9];
    const float* gamma = (const float*)d_in[10];
    const float* beta  = (const float*)d_in[11];
    float* out = (float*)d_out;

    const int N = NN, E = EE;
    const size_t ND = (size_t)N * 64;

    char* p = (char*)d_ws;
    float* fQ = (float*)p;           p += ND * 4;   // q; doubles as layer x-output
    float* fS = (float*)p;           p += ND * 4;   // skip
    float* fI = (float*)p;           p += ND * 4;   // x_init
    unsigned short* fK = (unsigned short*)p; p += ND * 2;
    unsigned short* fV = (unsigned short*)p; p += ND * 2;
    int* iOff = (int*)p; p += (size_t)(N + 1) * 4;
    int* iCnt = (int*)p; p += (size_t)N * 4;
    int* iPar = (int*)p; p += 1024 * 4;
    int* iSrc = (int*)p; p += (size_t)E * 4;

    // ---- CSR build (dst is layer-invariant) ----
    hipMemsetAsync(iCnt, 0, (size_t)N * 4, stream);
    hist_kernel<<<2048, 256, 0, stream>>>(ei, iCnt, E);
    int scan_n = N + 1;
    int nb = (scan_n + 1023) / 1024;
    scan_block<<<nb, 1024, 0, stream>>>(iCnt, iOff, iPar, scan_n);
    scan_part<<<1, 64, 0, stream>>>(iPar, nb);
    scan_add<<<(scan_n + 255) / 256, 256, 0, stream>>>(iOff, iPar, scan_n);
    hipMemsetAsync(iCnt, 0, (size_t)N * 4, stream);
    scatter_kernel<<<2048, 256, 0, stream>>>(ei, iCnt, iOff, iSrc, E);

    // ---- 3 layers ----
    const float* xin = x;
    for (int l = 0; l < 3; l++) {
        gemm4_mfma<<<(N + 63) / 64, 256, 0, stream>>>(xin, N,
            Wq + l * 4096, Wk + l * 4096, Wv + l * 4096, Wsk + l * 4096,
            bq + l * 64,   bk + l * 64,   bv + l * 64,   bsk + l * 64,
            fQ, fK, fV, fS);
        float* xout = (l == 2) ? out : fQ;
        node_attn<<<(N * 16 + 255) / 256, 256, 0, stream>>>(iOff, iSrc, fQ, fK, fV, fS,
            gamma + l * 64, beta + l * 64, fI, xout, l, N);
        xin = fQ;
    }
}